// Round 3
// baseline (391.884 us; speedup 1.0000x reference)
//
#include <hip/hip_runtime.h>
#include <math.h>

#define S 1024
#define D 64

__device__ __forceinline__ float waveSum(float v){
  #pragma unroll
  for(int o=32;o>0;o>>=1) v += __shfl_xor(v,o,64);
  return v;
}
__device__ __forceinline__ float waveMin(float v){
  #pragma unroll
  for(int o=32;o>0;o>>=1) v = fminf(v,__shfl_xor(v,o,64));
  return v;
}
// 256-thread block reductions (4 waves). Leading sync guards LDS reuse.
__device__ __forceinline__ float blockSum256(float v, float* red){
  float w = waveSum(v);
  int wid = threadIdx.x>>6;
  __syncthreads();
  if((threadIdx.x&63)==0) red[wid]=w;
  __syncthreads();
  return red[0]+red[1]+red[2]+red[3];
}
__device__ __forceinline__ float blockMin256(float v, float* red){
  float w = waveMin(v);
  int wid = threadIdx.x>>6;
  __syncthreads();
  if((threadIdx.x&63)==0) red[wid]=w;
  __syncthreads();
  return fminf(fminf(red[0],red[1]),fminf(red[2],red[3]));
}

// K1: q/k/v projections, expmap0(q), expmap0(k), squared norms, v_r init
__global__ __launch_bounds__(64) void k_proj(
  const float* __restrict__ qin, const float* __restrict__ kin, const float* __restrict__ vin,
  const float* __restrict__ Wq, const float* __restrict__ bq,
  const float* __restrict__ Wk, const float* __restrict__ bk,
  const float* __restrict__ Wv, const float* __restrict__ bv,
  const float* __restrict__ vrand,
  float* __restrict__ q_hyp, float* __restrict__ k_hyp,
  float* __restrict__ vproj, float* __restrict__ kproj,
  float* __restrict__ q2, float* __restrict__ k2, float* __restrict__ v_r)
{
  const int i = blockIdx.x, d = threadIdx.x;
  __shared__ float lq[D], lk[D], lv[D];
  lq[d]=qin[i*D+d]; lk[d]=kin[i*D+d]; lv[d]=vin[i*D+d];
  __syncthreads();
  float aq=bq[d], ak=bk[d], av=bv[d];
  const float4* wq4=(const float4*)(Wq + d*D);
  const float4* wk4=(const float4*)(Wk + d*D);
  const float4* wv4=(const float4*)(Wv + d*D);
  #pragma unroll
  for(int e=0;e<16;e++){
    float4 a=wq4[e], b=wk4[e], c=wv4[e];
    aq += lq[4*e]*a.x + lq[4*e+1]*a.y + lq[4*e+2]*a.z + lq[4*e+3]*a.w;
    ak += lk[4*e]*b.x + lk[4*e+1]*b.y + lk[4*e+2]*b.z + lk[4*e+3]*b.w;
    av += lv[4*e]*c.x + lv[4*e+1]*c.y + lv[4*e+2]*c.z + lv[4*e+3]*c.w;
  }
  // expmap0(q)
  float nq = sqrtf(waveSum(aq*aq)+1e-15f);
  float qh = tanhf(nq)*aq/nq;
  q_hyp[i*D+d]=qh;
  float q2v = waveSum(qh*qh);
  if(d==0) q2[i]=q2v;
  // expmap0(k)
  float nk = sqrtf(waveSum(ak*ak)+1e-15f);
  float kh = tanhf(nk)*ak/nk;
  k_hyp[i*D+d]=kh;
  float k2v = waveSum(kh*kh);
  if(d==0) k2[i]=k2v;
  vproj[i*D+d]=av;
  kproj[i*D+d]=ak;
  // v_r = normalize(v_rand_init) over D, eps=1e-12
  float vr = vrand[i*D+d];
  float nn = sqrtf(waveSum(vr*vr));
  v_r[i*D+d] = vr/fmaxf(nn,1e-12f);
}

// K2: dist row -> min -> w_un -> w_sum -> entropy/eff_mass. One block per query.
__global__ __launch_bounds__(256) void k_weights(
  const float* __restrict__ q_hyp, const float* __restrict__ k_hyp,
  const float* __restrict__ q2a, const float* __restrict__ k2a,
  float* __restrict__ wbuf, float* __restrict__ wsum, float* __restrict__ effm)
{
  const int i=blockIdx.x, tid=threadIdx.x;
  __shared__ float qv[D];
  __shared__ float red[4];
  if(tid<D) qv[tid]=q_hyp[i*D+tid];
  __syncthreads();
  const float x2=q2a[i];
  const float B=1.f-x2;
  float dist[4];
  float mn=3.4e38f;
  #pragma unroll
  for(int t=0;t<4;t++){
    const int j=tid+t*256;
    const float4* yr=(const float4*)(k_hyp + j*D);
    float dot=0.f;
    #pragma unroll
    for(int e=0;e<16;e++){
      float4 y=yr[e];
      dot += qv[4*e]*y.x + qv[4*e+1]*y.y + qv[4*e+2]*y.z + qv[4*e+3]*y.w;
    }
    const float y2=k2a[j];
    const float A=1.f-2.f*dot+y2;
    const float den=fmaxf(1.f-2.f*dot+x2*y2,1e-15f);
    const float num2=fmaxf(A*A*x2 + B*B*y2 - 2.f*A*B*dot, 0.f);
    const float nn=sqrtf(num2/(den*den)+1e-15f);
    dist[t]=2.f*atanhf(fminf(nn,0.99999994f));
    mn=fminf(mn,dist[t]);
  }
  mn=blockMin256(mn,red);
  float w[4]; float s=0.f;
  #pragma unroll
  for(int t=0;t<4;t++){
    w[t]=expf(mn-dist[t]);
    s+=w[t];
    wbuf[(size_t)i*S + tid + t*256]=w[t];
  }
  s=blockSum256(s,red)+1e-8f;
  if(tid==0) wsum[i]=s;
  const float inv=1.f/s;
  float ent=0.f;
  #pragma unroll
  for(int t=0;t<4;t++){
    const float pp=w[t]*inv;
    ent -= pp*logf(pp+1e-8f);
  }
  ent=blockSum256(ent,red);
  if(tid==0) effm[i]=expf(ent);
}

// K3: h = Wp @ v, centroid = Wp @ k_pre, then expmap0(centroid). 4 rows/block (1 wave each).
__global__ __launch_bounds__(256) void k_hcent(
  const float* __restrict__ wbuf, const float* __restrict__ wsum,
  const float* __restrict__ vproj, const float* __restrict__ kproj,
  float* __restrict__ h, float* __restrict__ c_hyp, float* __restrict__ c2)
{
  const int r=threadIdx.x>>6, d=threadIdx.x&63;
  const int i=blockIdx.x*4+r;
  const float inv=1.f/wsum[i];
  const float* wr = wbuf + (size_t)i*S;
  float ha=0.f, ca=0.f;
  #pragma unroll 8
  for(int j=0;j<S;j++){
    const float w=wr[j]*inv;
    ha += w*vproj[j*D+d];
    ca += w*kproj[j*D+d];
  }
  h[i*D+d]=ha;
  const float n=sqrtf(waveSum(ca*ca)+1e-15f);
  const float ch=tanhf(n)*ca/n;
  c_hyp[i*D+d]=ch;
  const float c2v=waveSum(ch*ch);
  if(d==0) c2[i]=c2v;
}

// K4 (mega): per query —
//  phase1: a,b coefficients (LDS only), var, tension, A2
//  phase2: Gram B = sum b^2 y y^T (64x64 in LDS) + u = sum a*b*y (LDS)
//  phase3: 3 power iterations: v' = c*(cdot*A2 + u.v) + cdot*u + B*v (wave0, tiny)
//  phase4: bifurcation epilogue + output GEMV (wave0)
__global__ __launch_bounds__(256,2) void k_mega(
  const float* __restrict__ c_hyp, const float* __restrict__ k_hyp,
  const float* __restrict__ c2a, const float* __restrict__ k2a,
  const float* __restrict__ wbuf, const float* __restrict__ wsum,
  const float* __restrict__ effm, const float* __restrict__ tau_p,
  const float* __restrict__ h, const float* __restrict__ q_hyp,
  const float* __restrict__ q2a, const float* __restrict__ v_r,
  const float* __restrict__ gu, const float* __restrict__ gamma_p,
  const float* __restrict__ ts_p, const float* __restrict__ Wo,
  const float* __restrict__ bo, float* __restrict__ out)
{
  const int i=blockIdx.x, tid=threadIdx.x;
  __shared__ float cv[D];
  __shared__ float b2l[S];      // b_j^2
  __shared__ float abl[S];      // a_j*b_j
  __shared__ float ychunk[64*64];   // raw y chunk
  __shared__ float ybchunk[64*64];  // b^2-scaled y chunk
  __shared__ float Bl[64*65];   // padded Gram
  __shared__ float ul[D];
  __shared__ float vvb[D];
  __shared__ float red[4];
  __shared__ float scal[4];     // var, A2, tension

  if(tid<D) cv[tid]=c_hyp[i*D+tid];
  __syncthreads();
  const float x2=c2a[i];
  const float Bc=1.f-x2;
  const float maxB=fmaxf(Bc,1e-15f);
  const float inv=1.f/wsum[i];
  const float4* cv4=(const float4*)cv;

  // ---- phase 1: coefficients ----
  float var=0.f, a2p=0.f;
  #pragma unroll
  for(int t=0;t<4;t++){
    const int j=tid+t*256;
    const float4* yr=(const float4*)(k_hyp + j*D);
    float dot=0.f;
    #pragma unroll 4
    for(int e=0;e<16;e++){
      float4 y=yr[e];
      float4 c=cv4[e];
      dot += c.x*y.x + c.y*y.y + c.z*y.z + c.w*y.w;
    }
    const float y2=k2a[j];
    const float A=1.f-2.f*dot+y2;
    const float den=fmaxf(1.f-2.f*dot+x2*y2,1e-15f);
    const float num2=fmaxf(A*A*x2 + Bc*Bc*y2 - 2.f*A*Bc*dot, 0.f);
    const float nn=sqrtf(num2/(den*den)+1e-15f);
    const float art=atanhf(fminf(nn,0.99999994f));
    const float c2k=2.f*art;
    const float w=wbuf[(size_t)i*S+j];
    var += (w*inv)*c2k*c2k;
    const float coef=sqrtf(w+1e-8f)*maxB*art/(nn*den);
    const float a=-coef*A, b=coef*Bc;
    b2l[j]=b*b; abl[j]=a*b;
    a2p += a*a;
  }
  var=blockSum256(var,red);
  a2p=blockSum256(a2p,red);
  if(tid==0){ scal[0]=var; scal[1]=a2p; scal[2]=var - tau_p[0]*effm[i]; }

  // ---- phase 2: Gram B and u ----
  const int tr=tid>>4, tc=tid&15;
  const int tr4=tr*4, tc4=tc*4;
  float4 acc0={0,0,0,0}, acc1={0,0,0,0}, acc2={0,0,0,0}, acc3={0,0,0,0};
  float4 uq={0,0,0,0};
  for(int ch=0; ch<16; ++ch){
    __syncthreads();   // protect chunk buffers (and publishes scal on first pass)
    #pragma unroll
    for(int t=0;t<4;t++){
      const int idx=tid+256*t;          // float4 index in 4096-float chunk
      float4 y=((const float4*)(k_hyp + ch*4096))[idx];
      const int row=idx>>4;
      const float b2=b2l[ch*64+row];
      ((float4*)ychunk)[idx]=y;
      float4 yb; yb.x=b2*y.x; yb.y=b2*y.y; yb.z=b2*y.z; yb.w=b2*y.w;
      ((float4*)ybchunk)[idx]=yb;
    }
    __syncthreads();
    #pragma unroll 4
    for(int jl=0;jl<64;jl++){
      const float4 yr=*(const float4*)(ybchunk + jl*64 + tr4);
      const float4 yc=*(const float4*)(ychunk  + jl*64 + tc4);
      acc0.x+=yr.x*yc.x; acc0.y+=yr.x*yc.y; acc0.z+=yr.x*yc.z; acc0.w+=yr.x*yc.w;
      acc1.x+=yr.y*yc.x; acc1.y+=yr.y*yc.y; acc1.z+=yr.y*yc.z; acc1.w+=yr.y*yc.w;
      acc2.x+=yr.z*yc.x; acc2.y+=yr.z*yc.y; acc2.z+=yr.z*yc.z; acc2.w+=yr.z*yc.w;
      acc3.x+=yr.w*yc.x; acc3.y+=yr.w*yc.y; acc3.z+=yr.w*yc.z; acc3.w+=yr.w*yc.w;
      if(tr==0){
        const float ab=abl[ch*64+jl];
        uq.x+=ab*yc.x; uq.y+=ab*yc.y; uq.z+=ab*yc.z; uq.w+=ab*yc.w;
      }
    }
  }
  __syncthreads();
  Bl[(tr4+0)*65+tc4+0]=acc0.x; Bl[(tr4+0)*65+tc4+1]=acc0.y; Bl[(tr4+0)*65+tc4+2]=acc0.z; Bl[(tr4+0)*65+tc4+3]=acc0.w;
  Bl[(tr4+1)*65+tc4+0]=acc1.x; Bl[(tr4+1)*65+tc4+1]=acc1.y; Bl[(tr4+1)*65+tc4+2]=acc1.z; Bl[(tr4+1)*65+tc4+3]=acc1.w;
  Bl[(tr4+2)*65+tc4+0]=acc2.x; Bl[(tr4+2)*65+tc4+1]=acc2.y; Bl[(tr4+2)*65+tc4+2]=acc2.z; Bl[(tr4+2)*65+tc4+3]=acc2.w;
  Bl[(tr4+3)*65+tc4+0]=acc3.x; Bl[(tr4+3)*65+tc4+1]=acc3.y; Bl[(tr4+3)*65+tc4+2]=acc3.z; Bl[(tr4+3)*65+tc4+3]=acc3.w;
  if(tr==0){ ul[tc4]=uq.x; ul[tc4+1]=uq.y; ul[tc4+2]=uq.z; ul[tc4+3]=uq.w; }
  __syncthreads();

  // ---- phase 3: 3 power iterations (wave0) ----
  const float vars=scal[0], A2s=scal[1], tns=scal[2];
  float vd=0.f, cd=0.f, ud=0.f;
  if(tid<D){ vd=v_r[i*D+tid]; cd=cv[tid]; ud=ul[tid]; }
  for(int it=0; it<3; ++it){
    __syncthreads();
    if(tid<D) vvb[tid]=vd;
    __syncthreads();
    if(tid<D){
      const float cdot=waveSum(cd*vd);
      const float uv=waveSum(ud*vd);
      float bv=0.f;
      const float* brow=Bl + tid*65;
      #pragma unroll 8
      for(int e=0;e<D;e++) bv += brow[e]*vvb[e];
      const float nv = cd*(cdot*A2s+uv) + cdot*ud + bv;
      const float nn=sqrtf(waveSum(nv*nv));
      vd=nv/fmaxf(nn,1e-12f);
    }
  }

  // ---- phase 4: epilogue (wave0) ----
  __syncthreads();
  if(tid<D){
    const int d=tid;
    const float hd=h[i*D+d];
    const float qd=q_hyp[i*D+d];
    const float q2=q2a[i];
    // transp0back
    const float wpg=vd/fmaxf(1.f-x2,1e-15f);
    // fallback = normalize(logmap0(q) - logmap0(c))
    const float nq=sqrtf(q2+1e-15f);
    const float qt=atanhf(fminf(nq,0.99999994f))*qd/nq;
    const float ncn=sqrtf(x2+1e-15f);
    const float ct=atanhf(fminf(ncn,0.99999994f))*cv[d]/ncn;
    const float df=qt-ct;
    const float nd=sqrtf(waveSum(df*df));
    const float fb=df/fmaxf(nd,1e-8f);
    const float wp=(vars>1e-5f)?wpg:fb;
    // h_comp
    const float hn=sqrtf(waveSum(hd*hd)+1e-15f);
    const float hc=asinhf(hn)*hd/(hn+1e-8f);
    const float x=waveSum(hc*wp);
    const float hmag=sqrtf(waveSum(hc*hc)+1e-15f);
    const float amp=(tns>0.f)? hmag*tanhf(tns) : 0.f;
    const float u0=gu[i*2], u1=gu[i*2+1];
    const float eg=(u0>=u1)?1.f:-1.f;
    const float dc=tanhf(eg*amp - x);
    const float hp=hc+dc*wp;
    const float hpn=sqrtf(waveSum(hp*hp)+1e-15f)+1e-8f;
    const float hpb=hp*(tanhf(hpn*ts_p[0])/hpn);
    const float n2=sqrtf(waveSum(hpb*hpb)+1e-15f);
    const float hyp=tanhf(n2)*hpb/n2;
    const float n3=sqrtf(waveSum(hyp*hyp)+1e-15f);
    const float bif=atanhf(fminf(n3,0.99999994f))*hyp/n3;
    const float gate=1.f/(1.f+expf(-gamma_p[0]));
    vvb[d]=(1.f-gate)*hd + gate*bif;
  }
  __syncthreads();
  if(tid<D){
    float acc=bo[tid];
    const float4* wo4=(const float4*)(Wo + tid*D);
    #pragma unroll
    for(int e=0;e<16;e++){
      float4 wv=wo4[e];
      acc += vvb[4*e]*wv.x + vvb[4*e+1]*wv.y + vvb[4*e+2]*wv.z + vvb[4*e+3]*wv.w;
    }
    out[i*D+tid]=acc;
  }
}

extern "C" void kernel_launch(void* const* d_in, const int* in_sizes, int n_in,
                              void* d_out, int out_size, void* d_ws, size_t ws_size,
                              hipStream_t stream)
{
  const float* qin=(const float*)d_in[0];
  const float* kin=(const float*)d_in[1];
  const float* vin=(const float*)d_in[2];
  const float* Wq=(const float*)d_in[3];
  const float* bq=(const float*)d_in[4];
  const float* Wk=(const float*)d_in[5];
  const float* bk=(const float*)d_in[6];
  const float* Wv=(const float*)d_in[7];
  const float* bv=(const float*)d_in[8];
  const float* Wo=(const float*)d_in[9];
  const float* bo=(const float*)d_in[10];
  const float* tau=(const float*)d_in[11];
  const float* gamma=(const float*)d_in[12];
  const float* tscale=(const float*)d_in[13];
  const float* gu=(const float*)d_in[14];
  const float* vrand=(const float*)d_in[15];
  float* out=(float*)d_out;

  float* p=(float*)d_ws;
  float* q_hyp=p; p+=S*D;
  float* k_hyp=p; p+=S*D;
  float* vproj=p; p+=S*D;
  float* kproj=p; p+=S*D;
  float* v_r=p;   p+=S*D;
  float* h=p;     p+=S*D;
  float* c_hyp=p; p+=S*D;
  float* q2=p;   p+=S;
  float* k2=p;   p+=S;
  float* c2=p;   p+=S;
  float* wsum=p; p+=S;
  float* effm=p; p+=S;
  float* wbuf=p; p+=(size_t)S*S;

  k_proj<<<S,64,0,stream>>>(qin,kin,vin,Wq,bq,Wk,bk,Wv,bv,vrand,
                            q_hyp,k_hyp,vproj,kproj,q2,k2,v_r);
  k_weights<<<S,256,0,stream>>>(q_hyp,k_hyp,q2,k2,wbuf,wsum,effm);
  k_hcent<<<S/4,256,0,stream>>>(wbuf,wsum,vproj,kproj,h,c_hyp,c2);
  k_mega<<<S,256,0,stream>>>(c_hyp,k_hyp,c2,k2,wbuf,wsum,effm,tau,
                             h,q_hyp,q2,v_r,gu,gamma,tscale,Wo,bo,out);
}

// Round 4
// 178.397 us; speedup vs baseline: 2.1967x; 2.1967x over previous
//
#include <hip/hip_runtime.h>
#include <math.h>

#define S 1024
#define D 64
#define QB 2

__device__ __forceinline__ float waveSum(float v){
  #pragma unroll
  for(int o=32;o>0;o>>=1) v += __shfl_xor(v,o,64);
  return v;
}
__device__ __forceinline__ float waveMin(float v){
  #pragma unroll
  for(int o=32;o>0;o>>=1) v = fminf(v,__shfl_xor(v,o,64));
  return v;
}
// 256-thread block reductions (4 waves). Leading sync guards LDS reuse.
__device__ __forceinline__ float blockSum256(float v, float* red){
  float w = waveSum(v);
  int wid = threadIdx.x>>6;
  __syncthreads();
  if((threadIdx.x&63)==0) red[wid]=w;
  __syncthreads();
  return red[0]+red[1]+red[2]+red[3];
}
__device__ __forceinline__ float blockMin256(float v, float* red){
  float w = waveMin(v);
  int wid = threadIdx.x>>6;
  __syncthreads();
  if((threadIdx.x&63)==0) red[wid]=w;
  __syncthreads();
  return fminf(fminf(red[0],red[1]),fminf(red[2],red[3]));
}

// K1: q/k/v projections, expmap0(q), expmap0(k), squared norms, v_r init
__global__ __launch_bounds__(64) void k_proj(
  const float* __restrict__ qin, const float* __restrict__ kin, const float* __restrict__ vin,
  const float* __restrict__ Wq, const float* __restrict__ bq,
  const float* __restrict__ Wk, const float* __restrict__ bk,
  const float* __restrict__ Wv, const float* __restrict__ bv,
  const float* __restrict__ vrand,
  float* __restrict__ q_hyp, float* __restrict__ k_hyp,
  float* __restrict__ vproj, float* __restrict__ kproj,
  float* __restrict__ q2, float* __restrict__ k2, float* __restrict__ v_r)
{
  const int i = blockIdx.x, d = threadIdx.x;
  __shared__ __align__(16) float lq[D], lk[D], lv[D];
  lq[d]=qin[i*D+d]; lk[d]=kin[i*D+d]; lv[d]=vin[i*D+d];
  __syncthreads();
  float aq=bq[d], ak=bk[d], av=bv[d];
  const float4* wq4=(const float4*)(Wq + d*D);
  const float4* wk4=(const float4*)(Wk + d*D);
  const float4* wv4=(const float4*)(Wv + d*D);
  #pragma unroll
  for(int e=0;e<16;e++){
    float4 a=wq4[e], b=wk4[e], c=wv4[e];
    aq += lq[4*e]*a.x + lq[4*e+1]*a.y + lq[4*e+2]*a.z + lq[4*e+3]*a.w;
    ak += lk[4*e]*b.x + lk[4*e+1]*b.y + lk[4*e+2]*b.z + lk[4*e+3]*b.w;
    av += lv[4*e]*c.x + lv[4*e+1]*c.y + lv[4*e+2]*c.z + lv[4*e+3]*c.w;
  }
  // expmap0(q)
  float nq = sqrtf(waveSum(aq*aq)+1e-15f);
  float qh = tanhf(nq)*aq/nq;
  q_hyp[i*D+d]=qh;
  float q2v = waveSum(qh*qh);
  if(d==0) q2[i]=q2v;
  // expmap0(k)
  float nk = sqrtf(waveSum(ak*ak)+1e-15f);
  float kh = tanhf(nk)*ak/nk;
  k_hyp[i*D+d]=kh;
  float k2v = waveSum(kh*kh);
  if(d==0) k2[i]=k2v;
  vproj[i*D+d]=av;
  kproj[i*D+d]=ak;
  // v_r = normalize(v_rand_init) over D, eps=1e-12
  float vr = vrand[i*D+d];
  float nn = sqrtf(waveSum(vr*vr));
  v_r[i*D+d] = vr/fmaxf(nn,1e-12f);
}

// K2: dist row -> min -> w_un -> w_sum -> entropy/eff_mass. One block per query.
__global__ __launch_bounds__(256) void k_weights(
  const float* __restrict__ q_hyp, const float* __restrict__ k_hyp,
  const float* __restrict__ q2a, const float* __restrict__ k2a,
  float* __restrict__ wbuf, float* __restrict__ wsum, float* __restrict__ effm)
{
  const int i=blockIdx.x, tid=threadIdx.x;
  __shared__ __align__(16) float qv[D];
  __shared__ float red[4];
  if(tid<D) qv[tid]=q_hyp[i*D+tid];
  __syncthreads();
  const float x2=q2a[i];
  const float B=1.f-x2;
  float dist[4];
  float mn=3.4e38f;
  #pragma unroll
  for(int t=0;t<4;t++){
    const int j=tid+t*256;
    const float4* yr=(const float4*)(k_hyp + j*D);
    float dot=0.f;
    #pragma unroll
    for(int e=0;e<16;e++){
      float4 y=yr[e];
      dot += qv[4*e]*y.x + qv[4*e+1]*y.y + qv[4*e+2]*y.z + qv[4*e+3]*y.w;
    }
    const float y2=k2a[j];
    const float A=1.f-2.f*dot+y2;
    const float den=fmaxf(1.f-2.f*dot+x2*y2,1e-15f);
    const float num2=fmaxf(A*A*x2 + B*B*y2 - 2.f*A*B*dot, 0.f);
    const float nn=sqrtf(num2/(den*den)+1e-15f);
    dist[t]=2.f*atanhf(fminf(nn,0.99999994f));
    mn=fminf(mn,dist[t]);
  }
  mn=blockMin256(mn,red);
  float w[4]; float s=0.f;
  #pragma unroll
  for(int t=0;t<4;t++){
    w[t]=expf(mn-dist[t]);
    s+=w[t];
    wbuf[(size_t)i*S + tid + t*256]=w[t];
  }
  s=blockSum256(s,red)+1e-8f;
  if(tid==0) wsum[i]=s;
  const float inv=1.f/s;
  float ent=0.f;
  #pragma unroll
  for(int t=0;t<4;t++){
    const float pp=w[t]*inv;
    ent -= pp*logf(pp+1e-8f);
  }
  ent=blockSum256(ent,red);
  if(tid==0) effm[i]=expf(ent);
}

// K3: h = Wp @ v, centroid = Wp @ k_pre, then expmap0(centroid). 4 rows/block (1 wave each).
__global__ __launch_bounds__(256) void k_hcent(
  const float* __restrict__ wbuf, const float* __restrict__ wsum,
  const float* __restrict__ vproj, const float* __restrict__ kproj,
  float* __restrict__ h, float* __restrict__ c_hyp, float* __restrict__ c2)
{
  const int r=threadIdx.x>>6, d=threadIdx.x&63;
  const int i=blockIdx.x*4+r;
  const float inv=1.f/wsum[i];
  const float* wr = wbuf + (size_t)i*S;
  float ha=0.f, ca=0.f;
  #pragma unroll 8
  for(int j=0;j<S;j++){
    const float w=wr[j]*inv;
    ha += w*vproj[j*D+d];
    ca += w*kproj[j*D+d];
  }
  h[i*D+d]=ha;
  const float n=sqrtf(waveSum(ca*ca)+1e-15f);
  const float ch=tanhf(n)*ca/n;
  c_hyp[i*D+d]=ch;
  const float c2v=waveSum(ch*ch);
  if(d==0) c2[i]=c2v;
}

// K4 (fused): per block = QB queries.
//  phase A: a,b coefficients into LDS (shared y sweep), var, tension
//  phase B: 3 power iterations, y sweeps shared across QB queries
//  phase C: bifurcation epilogue + output GEMV
__global__ __launch_bounds__(256,4) void k_pmega(
  const float* __restrict__ c_hyp, const float* __restrict__ k_hyp,
  const float* __restrict__ c2a, const float* __restrict__ k2a,
  const float* __restrict__ wbuf, const float* __restrict__ wsum,
  const float* __restrict__ effm, const float* __restrict__ tau_p,
  const float* __restrict__ h, const float* __restrict__ q_hyp,
  const float* __restrict__ q2a, const float* __restrict__ v_r,
  const float* __restrict__ gu, const float* __restrict__ gamma_p,
  const float* __restrict__ ts_p, const float* __restrict__ Wo,
  const float* __restrict__ bo, float* __restrict__ out)
{
  const int i0=blockIdx.x*QB, tid=threadIdx.x;
  __shared__ __align__(16) float cv[QB][D];
  __shared__ __align__(16) float2 ab[QB][S];
  __shared__ __align__(16) float prow[QB][S];
  __shared__ __align__(16) float part[16][QB][D];
  __shared__ __align__(16) float vv[QB][D];
  __shared__ __align__(16) float fus[QB][D];
  __shared__ float red[4];
  __shared__ float scal[QB][4];   // 0:var 1:tension 2:cdot

  if(tid<QB*D){ cv[tid>>6][tid&63]=c_hyp[i0*D+tid]; vv[tid>>6][tid&63]=v_r[i0*D+tid]; }
  __syncthreads();

  float x2[QB], Bc[QB], maxB[QB], invs[QB];
  #pragma unroll
  for(int q=0;q<QB;q++){
    x2[q]=c2a[i0+q]; Bc[q]=1.f-x2[q]; maxB[q]=fmaxf(Bc[q],1e-15f);
    invs[q]=1.f/wsum[i0+q];
  }
  const float4* c40=(const float4*)cv[0];
  const float4* c41=(const float4*)cv[1];

  // ---- phase A: coefficients ----
  float var[QB]={0.f,0.f};
  #pragma unroll 1
  for(int t=0;t<4;t++){
    const int j=tid+t*256;
    const float4* yr=(const float4*)(k_hyp + j*D);
    float dot[QB]={0.f,0.f};
    #pragma unroll 4
    for(int e=0;e<16;e++){
      float4 y=yr[e];
      float4 a0=c40[e], a1=c41[e];
      dot[0] += a0.x*y.x + a0.y*y.y + a0.z*y.z + a0.w*y.w;
      dot[1] += a1.x*y.x + a1.y*y.y + a1.z*y.z + a1.w*y.w;
    }
    const float y2=k2a[j];
    #pragma unroll
    for(int q=0;q<QB;q++){
      const float A=1.f-2.f*dot[q]+y2;
      const float den=fmaxf(1.f-2.f*dot[q]+x2[q]*y2,1e-15f);
      const float num2=fmaxf(A*A*x2[q] + Bc[q]*Bc[q]*y2 - 2.f*A*Bc[q]*dot[q], 0.f);
      const float nn=sqrtf(num2/(den*den)+1e-15f);
      const float art=atanhf(fminf(nn,0.99999994f));
      const float c2k=2.f*art;
      const float w=wbuf[(size_t)(i0+q)*S+j];
      var[q] += (w*invs[q])*c2k*c2k;
      const float coef=sqrtf(w+1e-8f)*maxB[q]*art/(nn*den);
      float2 t2; t2.x=-coef*A; t2.y=coef*Bc[q];
      ab[q][j]=t2;
    }
  }
  #pragma unroll
  for(int q=0;q<QB;q++){
    const float v=blockSum256(var[q],red);
    if(tid==0){ scal[q][0]=v; scal[q][1]=v - tau_p[0]*effm[i0+q]; }
  }

  // ---- phase B: 3 power iterations ----
  const int dq=tid&15, g=tid>>4;
  for(int it=0; it<3; ++it){
    __syncthreads();
    if(tid<QB*64){
      const int q=tid>>6, d=tid&63;
      const float cd=waveSum(cv[q][d]*vv[q][d]);
      if(d==0) scal[q][2]=cd;
    }
    __syncthreads();
    const float cdot0=scal[0][2], cdot1=scal[1][2];
    const float4* v40=(const float4*)vv[0];
    const float4* v41=(const float4*)vv[1];
    float sal0=0.f, sal1=0.f;
    #pragma unroll 1
    for(int t=0;t<4;t++){
      const int j=tid+t*256;
      const float4* yr=(const float4*)(k_hyp + j*D);
      float tt0=0.f, tt1=0.f;
      #pragma unroll 4
      for(int e=0;e<16;e++){
        float4 y=yr[e];
        float4 a0=v40[e], a1=v41[e];
        tt0 += a0.x*y.x + a0.y*y.y + a0.z*y.z + a0.w*y.w;
        tt1 += a1.x*y.x + a1.y*y.y + a1.z*y.z + a1.w*y.w;
      }
      const float2 ab0=ab[0][j], ab1=ab[1][j];
      const float p0=ab0.x*cdot0 + ab0.y*tt0;
      const float p1=ab1.x*cdot1 + ab1.y*tt1;
      prow[0][j]=p0*ab0.y; sal0 += p0*ab0.x;
      prow[1][j]=p1*ab1.y; sal1 += p1*ab1.x;
    }
    sal0=blockSum256(sal0,red);
    sal1=blockSum256(sal1,red);   // barriers also publish prow
    // pass 2: shared y loads across queries
    float4 a0={0,0,0,0}, a1={0,0,0,0};
    #pragma unroll 4
    for(int jj=0;jj<64;jj++){
      const int j=jj*16+g;
      const float4 y=((const float4*)(k_hyp + j*D))[dq];
      const float p0=prow[0][j], p1=prow[1][j];
      a0.x+=p0*y.x; a0.y+=p0*y.y; a0.z+=p0*y.z; a0.w+=p0*y.w;
      a1.x+=p1*y.x; a1.y+=p1*y.y; a1.z+=p1*y.z; a1.w+=p1*y.w;
    }
    *(float4*)&part[g][0][dq*4]=a0;
    *(float4*)&part[g][1][dq*4]=a1;
    __syncthreads();
    if(tid<QB*64){
      const int q=tid>>6, d=tid&63;
      float od=((q==0)?sal0:sal1)*cv[q][d];
      #pragma unroll
      for(int gg=0;gg<16;gg++) od += part[gg][q][d];
      const float nn=sqrtf(waveSum(od*od));
      vv[q][d]=od/fmaxf(nn,1e-12f);
    }
    __syncthreads();
  }

  // ---- phase C: epilogue ----
  if(tid<QB*64){
    const int q=tid>>6, d=tid&63;
    const int i=i0+q;
    const float vd=vv[q][d];
    const float vars=scal[q][0], tns=scal[q][1];
    const float hd=h[i*D+d];
    const float qd=q_hyp[i*D+d];
    const float q2=q2a[i];
    const float wpg=vd/fmaxf(1.f-x2[q],1e-15f);
    const float nq=sqrtf(q2+1e-15f);
    const float qt=atanhf(fminf(nq,0.99999994f))*qd/nq;
    const float ncn=sqrtf(x2[q]+1e-15f);
    const float ct=atanhf(fminf(ncn,0.99999994f))*cv[q][d]/ncn;
    const float df=qt-ct;
    const float nd=sqrtf(waveSum(df*df));
    const float fb=df/fmaxf(nd,1e-8f);
    const float wp=(vars>1e-5f)?wpg:fb;
    const float hn=sqrtf(waveSum(hd*hd)+1e-15f);
    const float hc=asinhf(hn)*hd/(hn+1e-8f);
    const float x=waveSum(hc*wp);
    const float hmag=sqrtf(waveSum(hc*hc)+1e-15f);
    const float amp=(tns>0.f)? hmag*tanhf(tns) : 0.f;
    const float u0=gu[i*2], u1=gu[i*2+1];
    const float eg=(u0>=u1)?1.f:-1.f;
    const float dc=tanhf(eg*amp - x);
    const float hp=hc+dc*wp;
    const float hpn=sqrtf(waveSum(hp*hp)+1e-15f)+1e-8f;
    const float hpb=hp*(tanhf(hpn*ts_p[0])/hpn);
    const float n2=sqrtf(waveSum(hpb*hpb)+1e-15f);
    const float hyp=tanhf(n2)*hpb/n2;
    const float n3=sqrtf(waveSum(hyp*hyp)+1e-15f);
    const float bif=atanhf(fminf(n3,0.99999994f))*hyp/n3;
    const float gate=1.f/(1.f+expf(-gamma_p[0]));
    fus[q][d]=(1.f-gate)*hd + gate*bif;
  }
  __syncthreads();
  if(tid<QB*64){
    const int q=tid>>6, d=tid&63;
    float acc=bo[d];
    const float4* wo4=(const float4*)(Wo + d*D);
    #pragma unroll
    for(int e=0;e<16;e++){
      float4 wv=wo4[e];
      acc += fus[q][4*e]*wv.x + fus[q][4*e+1]*wv.y + fus[q][4*e+2]*wv.z + fus[q][4*e+3]*wv.w;
    }
    out[(i0+q)*D+d]=acc;
  }
}

extern "C" void kernel_launch(void* const* d_in, const int* in_sizes, int n_in,
                              void* d_out, int out_size, void* d_ws, size_t ws_size,
                              hipStream_t stream)
{
  const float* qin=(const float*)d_in[0];
  const float* kin=(const float*)d_in[1];
  const float* vin=(const float*)d_in[2];
  const float* Wq=(const float*)d_in[3];
  const float* bq=(const float*)d_in[4];
  const float* Wk=(const float*)d_in[5];
  const float* bk=(const float*)d_in[6];
  const float* Wv=(const float*)d_in[7];
  const float* bv=(const float*)d_in[8];
  const float* Wo=(const float*)d_in[9];
  const float* bo=(const float*)d_in[10];
  const float* tau=(const float*)d_in[11];
  const float* gamma=(const float*)d_in[12];
  const float* tscale=(const float*)d_in[13];
  const float* gu=(const float*)d_in[14];
  const float* vrand=(const float*)d_in[15];
  float* out=(float*)d_out;

  float* p=(float*)d_ws;
  float* q_hyp=p; p+=S*D;
  float* k_hyp=p; p+=S*D;
  float* vproj=p; p+=S*D;
  float* kproj=p; p+=S*D;
  float* v_r=p;   p+=S*D;
  float* h=p;     p+=S*D;
  float* c_hyp=p; p+=S*D;
  float* q2=p;   p+=S;
  float* k2=p;   p+=S;
  float* c2=p;   p+=S;
  float* wsum=p; p+=S;
  float* effm=p; p+=S;
  float* wbuf=p; p+=(size_t)S*S;

  k_proj<<<S,64,0,stream>>>(qin,kin,vin,Wq,bq,Wk,bk,Wv,bv,vrand,
                            q_hyp,k_hyp,vproj,kproj,q2,k2,v_r);
  k_weights<<<S,256,0,stream>>>(q_hyp,k_hyp,q2,k2,wbuf,wsum,effm);
  k_hcent<<<S/4,256,0,stream>>>(wbuf,wsum,vproj,kproj,h,c_hyp,c2);
  k_pmega<<<S/QB,256,0,stream>>>(c_hyp,k_hyp,c2,k2,wbuf,wsum,effm,tau,
                                 h,q_hyp,q2,v_r,gu,gamma,tscale,Wo,bo,out);
}

// Round 5
// 124.133 us; speedup vs baseline: 3.1570x; 1.4371x over previous
//
#include <hip/hip_runtime.h>
#include <math.h>

#define S 1024
#define D 64

__device__ __forceinline__ float waveSum(float v){
  #pragma unroll
  for(int o=32;o>0;o>>=1) v += __shfl_xor(v,o,64);
  return v;
}
__device__ __forceinline__ float waveMin(float v){
  #pragma unroll
  for(int o=32;o>0;o>>=1) v = fminf(v,__shfl_xor(v,o,64));
  return v;
}
// 512-thread block reductions (8 waves). Leading sync guards LDS reuse.
__device__ __forceinline__ float blockSum512(float v, float* red){
  float w = waveSum(v);
  int wid = threadIdx.x>>6;
  __syncthreads();
  if((threadIdx.x&63)==0) red[wid]=w;
  __syncthreads();
  float s=0.f;
  #pragma unroll
  for(int k=0;k<8;k++) s+=red[k];
  return s;
}
__device__ __forceinline__ float blockMin512(float v, float* red){
  float w = waveMin(v);
  int wid = threadIdx.x>>6;
  __syncthreads();
  if((threadIdx.x&63)==0) red[wid]=w;
  __syncthreads();
  float s=red[0];
  #pragma unroll
  for(int k=1;k<8;k++) s=fminf(s,red[k]);
  return s;
}

// K1: q/k/v projections, expmap0(q), expmap0(k), squared norms, v_r init
__global__ __launch_bounds__(64) void k_proj(
  const float* __restrict__ qin, const float* __restrict__ kin, const float* __restrict__ vin,
  const float* __restrict__ Wq, const float* __restrict__ bq,
  const float* __restrict__ Wk, const float* __restrict__ bk,
  const float* __restrict__ Wv, const float* __restrict__ bv,
  const float* __restrict__ vrand,
  float* __restrict__ q_hyp, float* __restrict__ k_hyp,
  float* __restrict__ vproj, float* __restrict__ kproj,
  float* __restrict__ q2, float* __restrict__ k2, float* __restrict__ v_r)
{
  const int i = blockIdx.x, d = threadIdx.x;
  __shared__ __align__(16) float lq[D], lk[D], lv[D];
  lq[d]=qin[i*D+d]; lk[d]=kin[i*D+d]; lv[d]=vin[i*D+d];
  __syncthreads();
  float aq=bq[d], ak=bk[d], av=bv[d];
  const float4* wq4=(const float4*)(Wq + d*D);
  const float4* wk4=(const float4*)(Wk + d*D);
  const float4* wv4=(const float4*)(Wv + d*D);
  #pragma unroll
  for(int e=0;e<16;e++){
    float4 a=wq4[e], b=wk4[e], c=wv4[e];
    aq += lq[4*e]*a.x + lq[4*e+1]*a.y + lq[4*e+2]*a.z + lq[4*e+3]*a.w;
    ak += lk[4*e]*b.x + lk[4*e+1]*b.y + lk[4*e+2]*b.z + lk[4*e+3]*b.w;
    av += lv[4*e]*c.x + lv[4*e+1]*c.y + lv[4*e+2]*c.z + lv[4*e+3]*c.w;
  }
  float nq = sqrtf(waveSum(aq*aq)+1e-15f);
  float qh = tanhf(nq)*aq/nq;
  q_hyp[i*D+d]=qh;
  float q2v = waveSum(qh*qh);
  if(d==0) q2[i]=q2v;
  float nk = sqrtf(waveSum(ak*ak)+1e-15f);
  float kh = tanhf(nk)*ak/nk;
  k_hyp[i*D+d]=kh;
  float k2v = waveSum(kh*kh);
  if(d==0) k2[i]=k2v;
  vproj[i*D+d]=av;
  kproj[i*D+d]=ak;
  float vr = vrand[i*D+d];
  float nn = sqrtf(waveSum(vr*vr));
  v_r[i*D+d] = vr/fmaxf(nn,1e-12f);
}

// K2 (fused weights+hcent): 2 queries per block, 512 threads.
//  phase 1: dist -> min -> w -> wsum -> entropy (y sweep shared by 2 queries)
//  phase 2: h = Wp@vproj and centroid = Wp@kproj in ONE float4 sweep, + expmap0(centroid)
__global__ __launch_bounds__(512,4) void k_wc(
  const float* __restrict__ q_hyp, const float* __restrict__ k_hyp,
  const float* __restrict__ q2a, const float* __restrict__ k2a,
  const float* __restrict__ vproj, const float* __restrict__ kproj,
  float* __restrict__ wbuf, float* __restrict__ wsum, float* __restrict__ effm,
  float* __restrict__ h, float* __restrict__ c_hyp, float* __restrict__ c2)
{
  const int i0=blockIdx.x*2, tid=threadIdx.x;
  __shared__ __align__(16) float qv[2][D];
  __shared__ __align__(16) float wl[2][S];
  __shared__ __align__(16) float parth[32][2][D];
  __shared__ __align__(16) float partc[32][2][D];
  __shared__ float red[8];
  if(tid<128) qv[tid>>6][tid&63]=q_hyp[i0*D+tid];
  __syncthreads();
  const float x20=q2a[i0], x21=q2a[i0+1];
  const float B0=1.f-x20, B1=1.f-x21;
  const float4* qv40=(const float4*)qv[0];
  const float4* qv41=(const float4*)qv[1];
  float dist_r[2][2];
  float mn0=3.4e38f, mn1=3.4e38f;
  #pragma unroll
  for(int t=0;t<2;t++){
    const int j=tid+t*512;
    const float4* yr=(const float4*)(k_hyp + j*D);
    float d0=0.f, d1=0.f;
    #pragma unroll 4
    for(int e=0;e<16;e++){
      float4 y=yr[e];
      float4 a=qv40[e], b=qv41[e];
      d0 += a.x*y.x + a.y*y.y + a.z*y.z + a.w*y.w;
      d1 += b.x*y.x + b.y*y.y + b.z*y.z + b.w*y.w;
    }
    const float y2=k2a[j];
    {
      const float A=1.f-2.f*d0+y2;
      const float den=fmaxf(1.f-2.f*d0+x20*y2,1e-15f);
      const float num2=fmaxf(A*A*x20 + B0*B0*y2 - 2.f*A*B0*d0, 0.f);
      const float nn=sqrtf(num2/(den*den)+1e-15f);
      dist_r[t][0]=2.f*atanhf(fminf(nn,0.99999994f));
      mn0=fminf(mn0,dist_r[t][0]);
    }
    {
      const float A=1.f-2.f*d1+y2;
      const float den=fmaxf(1.f-2.f*d1+x21*y2,1e-15f);
      const float num2=fmaxf(A*A*x21 + B1*B1*y2 - 2.f*A*B1*d1, 0.f);
      const float nn=sqrtf(num2/(den*den)+1e-15f);
      dist_r[t][1]=2.f*atanhf(fminf(nn,0.99999994f));
      mn1=fminf(mn1,dist_r[t][1]);
    }
  }
  mn0=blockMin512(mn0,red);
  mn1=blockMin512(mn1,red);
  float s0=0.f, s1=0.f;
  float w_r[2][2];
  #pragma unroll
  for(int t=0;t<2;t++){
    const int j=tid+t*512;
    w_r[t][0]=expf(mn0-dist_r[t][0]);
    w_r[t][1]=expf(mn1-dist_r[t][1]);
    wl[0][j]=w_r[t][0]; wl[1][j]=w_r[t][1];
    wbuf[(size_t)i0*S+j]=w_r[t][0];
    wbuf[(size_t)(i0+1)*S+j]=w_r[t][1];
    s0+=w_r[t][0]; s1+=w_r[t][1];
  }
  s0=blockSum512(s0,red)+1e-8f;
  s1=blockSum512(s1,red)+1e-8f;
  if(tid==0){ wsum[i0]=s0; wsum[i0+1]=s1; }
  const float inv0=1.f/s0, inv1=1.f/s1;
  float e0=0.f, e1=0.f;
  #pragma unroll
  for(int t=0;t<2;t++){
    const float p0=w_r[t][0]*inv0; e0 -= p0*logf(p0+1e-8f);
    const float p1=w_r[t][1]*inv1; e1 -= p1*logf(p1+1e-8f);
  }
  e0=blockSum512(e0,red);
  e1=blockSum512(e1,red);
  if(tid==0){ effm[i0]=expf(e0); effm[i0+1]=expf(e1); }
  // ---- phase 2: h + centroid in one sweep (wl published by reduction barriers) ----
  const int dq=tid&15, g=tid>>4;
  float4 ah0={0,0,0,0}, ah1={0,0,0,0}, ac0={0,0,0,0}, ac1={0,0,0,0};
  #pragma unroll 4
  for(int jj=0;jj<32;jj++){
    const int j=jj*32+g;
    const float4 yv=((const float4*)(vproj + j*D))[dq];
    const float4 yk=((const float4*)(kproj + j*D))[dq];
    const float w0=wl[0][j], w1=wl[1][j];
    ah0.x+=w0*yv.x; ah0.y+=w0*yv.y; ah0.z+=w0*yv.z; ah0.w+=w0*yv.w;
    ah1.x+=w1*yv.x; ah1.y+=w1*yv.y; ah1.z+=w1*yv.z; ah1.w+=w1*yv.w;
    ac0.x+=w0*yk.x; ac0.y+=w0*yk.y; ac0.z+=w0*yk.z; ac0.w+=w0*yk.w;
    ac1.x+=w1*yk.x; ac1.y+=w1*yk.y; ac1.z+=w1*yk.z; ac1.w+=w1*yk.w;
  }
  *(float4*)&parth[g][0][dq*4]=ah0;
  *(float4*)&parth[g][1][dq*4]=ah1;
  *(float4*)&partc[g][0][dq*4]=ac0;
  *(float4*)&partc[g][1][dq*4]=ac1;
  __syncthreads();
  if(tid<128){
    const int q=tid>>6, d=tid&63;
    float hs=0.f, cs=0.f;
    #pragma unroll 8
    for(int gg=0;gg<32;gg++){ hs+=parth[gg][q][d]; cs+=partc[gg][q][d]; }
    const float invq = q ? inv1 : inv0;
    h[(i0+q)*D+d]=hs*invq;
    const float ca=cs*invq;
    const float n=sqrtf(waveSum(ca*ca)+1e-15f);
    const float ch=tanhf(n)*ca/n;
    c_hyp[(i0+q)*D+d]=ch;
    const float c2v=waveSum(ch*ch);
    if(d==0) c2[i0+q]=c2v;
  }
}

// K3 (fused ab+power+final): 2 queries per block, 512 threads, grid 512
//  phase A: a,b coefficients into LDS (shared y sweep), var, tension
//  phase B: 3 power iterations, y sweeps shared across 2 queries
//  phase C: bifurcation epilogue + output GEMV
__global__ __launch_bounds__(512,4) void k_pmega(
  const float* __restrict__ c_hyp, const float* __restrict__ k_hyp,
  const float* __restrict__ c2a, const float* __restrict__ k2a,
  const float* __restrict__ wbuf, const float* __restrict__ wsum,
  const float* __restrict__ effm, const float* __restrict__ tau_p,
  const float* __restrict__ h, const float* __restrict__ q_hyp,
  const float* __restrict__ q2a, const float* __restrict__ v_r,
  const float* __restrict__ gu, const float* __restrict__ gamma_p,
  const float* __restrict__ ts_p, const float* __restrict__ Wo,
  const float* __restrict__ bo, float* __restrict__ out)
{
  const int i0=blockIdx.x*2, tid=threadIdx.x;
  __shared__ __align__(16) float cv[2][D];
  __shared__ __align__(16) float vv[2][D];
  __shared__ __align__(16) float2 ab[2][S];
  __shared__ __align__(16) float prow[2][S];
  __shared__ __align__(16) float part[32][2][D];
  __shared__ __align__(16) float fus[2][D];
  __shared__ float red[8];
  __shared__ float scal[2][4];   // 0:var 1:tension 2:cdot

  if(tid<128){ cv[tid>>6][tid&63]=c_hyp[i0*D+tid]; vv[tid>>6][tid&63]=v_r[i0*D+tid]; }
  __syncthreads();

  const float x20=c2a[i0], x21=c2a[i0+1];
  const float Bc0=1.f-x20, Bc1=1.f-x21;
  const float mB0=fmaxf(Bc0,1e-15f), mB1=fmaxf(Bc1,1e-15f);
  const float inv0=1.f/wsum[i0], inv1=1.f/wsum[i0+1];
  const float4* c40=(const float4*)cv[0];
  const float4* c41=(const float4*)cv[1];

  // ---- phase A: coefficients ----
  float var0=0.f, var1=0.f;
  #pragma unroll 1
  for(int t=0;t<2;t++){
    const int j=tid+t*512;
    const float4* yr=(const float4*)(k_hyp + j*D);
    float d0=0.f, d1=0.f;
    #pragma unroll 4
    for(int e=0;e<16;e++){
      float4 y=yr[e];
      float4 a=c40[e], b=c41[e];
      d0 += a.x*y.x + a.y*y.y + a.z*y.z + a.w*y.w;
      d1 += b.x*y.x + b.y*y.y + b.z*y.z + b.w*y.w;
    }
    const float y2=k2a[j];
    {
      const float A=1.f-2.f*d0+y2;
      const float den=fmaxf(1.f-2.f*d0+x20*y2,1e-15f);
      const float num2=fmaxf(A*A*x20 + Bc0*Bc0*y2 - 2.f*A*Bc0*d0, 0.f);
      const float nn=sqrtf(num2/(den*den)+1e-15f);
      const float art=atanhf(fminf(nn,0.99999994f));
      const float w=wbuf[(size_t)i0*S+j];
      var0 += (w*inv0)*4.f*art*art;
      const float coef=sqrtf(w+1e-8f)*mB0*art/(nn*den);
      float2 t2; t2.x=-coef*A; t2.y=coef*Bc0;
      ab[0][j]=t2;
    }
    {
      const float A=1.f-2.f*d1+y2;
      const float den=fmaxf(1.f-2.f*d1+x21*y2,1e-15f);
      const float num2=fmaxf(A*A*x21 + Bc1*Bc1*y2 - 2.f*A*Bc1*d1, 0.f);
      const float nn=sqrtf(num2/(den*den)+1e-15f);
      const float art=atanhf(fminf(nn,0.99999994f));
      const float w=wbuf[(size_t)(i0+1)*S+j];
      var1 += (w*inv1)*4.f*art*art;
      const float coef=sqrtf(w+1e-8f)*mB1*art/(nn*den);
      float2 t2; t2.x=-coef*A; t2.y=coef*Bc1;
      ab[1][j]=t2;
    }
  }
  var0=blockSum512(var0,red);
  var1=blockSum512(var1,red);
  if(tid==0){
    scal[0][0]=var0; scal[0][1]=var0 - tau_p[0]*effm[i0];
    scal[1][0]=var1; scal[1][1]=var1 - tau_p[0]*effm[i0+1];
  }

  // ---- phase B: 3 power iterations ----
  const int dq=tid&15, g=tid>>4;
  for(int it=0; it<3; ++it){
    __syncthreads();   // vv ready (and scal on first pass)
    if(tid<128){
      const int q=tid>>6, d=tid&63;
      const float cd=waveSum(cv[q][d]*vv[q][d]);
      if(d==0) scal[q][2]=cd;
    }
    __syncthreads();
    const float cdot0=scal[0][2], cdot1=scal[1][2];
    const float4* v40=(const float4*)vv[0];
    const float4* v41=(const float4*)vv[1];
    float sal0=0.f, sal1=0.f;
    #pragma unroll 1
    for(int t=0;t<2;t++){
      const int j=tid+t*512;
      const float4* yr=(const float4*)(k_hyp + j*D);
      float tt0=0.f, tt1=0.f;
      #pragma unroll 4
      for(int e=0;e<16;e++){
        float4 y=yr[e];
        float4 a=v40[e], b=v41[e];
        tt0 += a.x*y.x + a.y*y.y + a.z*y.z + a.w*y.w;
        tt1 += b.x*y.x + b.y*y.y + b.z*y.z + b.w*y.w;
      }
      const float2 ab0=ab[0][j], ab1=ab[1][j];
      const float p0=ab0.x*cdot0 + ab0.y*tt0;
      const float p1=ab1.x*cdot1 + ab1.y*tt1;
      prow[0][j]=p0*ab0.y; sal0 += p0*ab0.x;
      prow[1][j]=p1*ab1.y; sal1 += p1*ab1.x;
    }
    sal0=blockSum512(sal0,red);
    sal1=blockSum512(sal1,red);   // barriers also publish prow
    // pass 2: shared y loads across queries; 32 j per thread
    float4 a0={0,0,0,0}, a1={0,0,0,0};
    #pragma unroll 4
    for(int jj=0;jj<32;jj++){
      const int j=jj*32+g;
      const float4 y=((const float4*)(k_hyp + j*D))[dq];
      const float p0=prow[0][j], p1=prow[1][j];
      a0.x+=p0*y.x; a0.y+=p0*y.y; a0.z+=p0*y.z; a0.w+=p0*y.w;
      a1.x+=p1*y.x; a1.y+=p1*y.y; a1.z+=p1*y.z; a1.w+=p1*y.w;
    }
    *(float4*)&part[g][0][dq*4]=a0;
    *(float4*)&part[g][1][dq*4]=a1;
    __syncthreads();
    if(tid<128){
      const int q=tid>>6, d=tid&63;
      float od=((q==0)?sal0:sal1)*cv[q][d];
      #pragma unroll 8
      for(int gg=0;gg<32;gg++) od += part[gg][q][d];
      const float nn=sqrtf(waveSum(od*od));
      vv[q][d]=od/fmaxf(nn,1e-12f);
    }
  }
  __syncthreads();

  // ---- phase C: epilogue ----
  if(tid<128){
    const int q=tid>>6, d=tid&63;
    const int i=i0+q;
    const float x2q = q ? x21 : x20;
    const float vd=vv[q][d];
    const float vars=scal[q][0], tns=scal[q][1];
    const float hd=h[i*D+d];
    const float qd=q_hyp[i*D+d];
    const float q2=q2a[i];
    const float wpg=vd/fmaxf(1.f-x2q,1e-15f);
    const float nq=sqrtf(q2+1e-15f);
    const float qt=atanhf(fminf(nq,0.99999994f))*qd/nq;
    const float ncn=sqrtf(x2q+1e-15f);
    const float ct=atanhf(fminf(ncn,0.99999994f))*cv[q][d]/ncn;
    const float df=qt-ct;
    const float nd=sqrtf(waveSum(df*df));
    const float fb=df/fmaxf(nd,1e-8f);
    const float wp=(vars>1e-5f)?wpg:fb;
    const float hn=sqrtf(waveSum(hd*hd)+1e-15f);
    const float hc=asinhf(hn)*hd/(hn+1e-8f);
    const float x=waveSum(hc*wp);
    const float hmag=sqrtf(waveSum(hc*hc)+1e-15f);
    const float amp=(tns>0.f)? hmag*tanhf(tns) : 0.f;
    const float u0=gu[i*2], u1=gu[i*2+1];
    const float eg=(u0>=u1)?1.f:-1.f;
    const float dc=tanhf(eg*amp - x);
    const float hp=hc+dc*wp;
    const float hpn=sqrtf(waveSum(hp*hp)+1e-15f)+1e-8f;
    const float hpb=hp*(tanhf(hpn*ts_p[0])/hpn);
    const float n2=sqrtf(waveSum(hpb*hpb)+1e-15f);
    const float hyp=tanhf(n2)*hpb/n2;
    const float n3=sqrtf(waveSum(hyp*hyp)+1e-15f);
    const float bif=atanhf(fminf(n3,0.99999994f))*hyp/n3;
    const float gate=1.f/(1.f+expf(-gamma_p[0]));
    fus[q][d]=(1.f-gate)*hd + gate*bif;
  }
  __syncthreads();
  if(tid<128){
    const int q=tid>>6, d=tid&63;
    float acc=bo[d];
    const float4* wo4=(const float4*)(Wo + d*D);
    #pragma unroll
    for(int e=0;e<16;e++){
      float4 wv=wo4[e];
      acc += fus[q][4*e]*wv.x + fus[q][4*e+1]*wv.y + fus[q][4*e+2]*wv.z + fus[q][4*e+3]*wv.w;
    }
    out[(i0+q)*D+d]=acc;
  }
}

extern "C" void kernel_launch(void* const* d_in, const int* in_sizes, int n_in,
                              void* d_out, int out_size, void* d_ws, size_t ws_size,
                              hipStream_t stream)
{
  const float* qin=(const float*)d_in[0];
  const float* kin=(const float*)d_in[1];
  const float* vin=(const float*)d_in[2];
  const float* Wq=(const float*)d_in[3];
  const float* bq=(const float*)d_in[4];
  const float* Wk=(const float*)d_in[5];
  const float* bk=(const float*)d_in[6];
  const float* Wv=(const float*)d_in[7];
  const float* bv=(const float*)d_in[8];
  const float* Wo=(const float*)d_in[9];
  const float* bo=(const float*)d_in[10];
  const float* tau=(const float*)d_in[11];
  const float* gamma=(const float*)d_in[12];
  const float* tscale=(const float*)d_in[13];
  const float* gu=(const float*)d_in[14];
  const float* vrand=(const float*)d_in[15];
  float* out=(float*)d_out;

  float* p=(float*)d_ws;
  float* q_hyp=p; p+=S*D;
  float* k_hyp=p; p+=S*D;
  float* vproj=p; p+=S*D;
  float* kproj=p; p+=S*D;
  float* v_r=p;   p+=S*D;
  float* h=p;     p+=S*D;
  float* c_hyp=p; p+=S*D;
  float* q2=p;   p+=S;
  float* k2=p;   p+=S;
  float* c2=p;   p+=S;
  float* wsum=p; p+=S;
  float* effm=p; p+=S;
  float* wbuf=p; p+=(size_t)S*S;

  k_proj<<<S,64,0,stream>>>(qin,kin,vin,Wq,bq,Wk,bk,Wv,bv,vrand,
                            q_hyp,k_hyp,vproj,kproj,q2,k2,v_r);
  k_wc<<<S/2,512,0,stream>>>(q_hyp,k_hyp,q2,k2,vproj,kproj,
                             wbuf,wsum,effm,h,c_hyp,c2);
  k_pmega<<<S/2,512,0,stream>>>(c_hyp,k_hyp,c2,k2,wbuf,wsum,effm,tau,
                                h,q_hyp,q2,v_r,gu,gamma,tscale,Wo,bo,out);
}

// Round 6
// 79.044 us; speedup vs baseline: 4.9578x; 1.5704x over previous
//
#include <hip/hip_runtime.h>
#include <math.h>

#define S 1024
#define D 64
#define BND 0.99999994f
#define FINF 3.4e38f
#define C4(v,c) ((&(v).x)[c])

__device__ __forceinline__ float waveSum(float v){
  #pragma unroll
  for(int o=32;o>0;o>>=1) v += __shfl_xor(v,o,64);
  return v;
}
__device__ __forceinline__ float waveMin(float v){
  #pragma unroll
  for(int o=32;o>0;o>>=1) v = fminf(v,__shfl_xor(v,o,64));
  return v;
}
// 512-thread block reductions (8 waves). Leading sync guards LDS reuse.
__device__ __forceinline__ float blockSum512(float v, float* red){
  float w = waveSum(v);
  int wid = threadIdx.x>>6;
  __syncthreads();
  if((threadIdx.x&63)==0) red[wid]=w;
  __syncthreads();
  float s=0.f;
  #pragma unroll
  for(int k=0;k<8;k++) s+=red[k];
  return s;
}
__device__ __forceinline__ float blockMin512(float v, float* red){
  float w = waveMin(v);
  int wid = threadIdx.x>>6;
  __syncthreads();
  if((threadIdx.x&63)==0) red[wid]=w;
  __syncthreads();
  float s=red[0];
  #pragma unroll
  for(int k=1;k<8;k++) s=fminf(s,red[k]);
  return s;
}
__device__ __forceinline__ float4 mk4(const float* a){
  float4 r; r.x=a[0]; r.y=a[1]; r.z=a[2]; r.w=a[3]; return r;
}

// K1: q/k/v projections, expmap0(q), expmap0(k), norms, v_r init, + transposed k_hypT
__global__ __launch_bounds__(64) void k_proj(
  const float* __restrict__ qin, const float* __restrict__ kin, const float* __restrict__ vin,
  const float* __restrict__ Wq, const float* __restrict__ bq,
  const float* __restrict__ Wk, const float* __restrict__ bk,
  const float* __restrict__ Wv, const float* __restrict__ bv,
  const float* __restrict__ vrand,
  float* __restrict__ q_hyp, float* __restrict__ k_hyp, float* __restrict__ kT,
  float* __restrict__ vproj, float* __restrict__ kproj,
  float* __restrict__ q2, float* __restrict__ k2, float* __restrict__ v_r)
{
  const int i = blockIdx.x, d = threadIdx.x;
  __shared__ __align__(16) float lq[D], lk[D], lv[D];
  lq[d]=qin[i*D+d]; lk[d]=kin[i*D+d]; lv[d]=vin[i*D+d];
  __syncthreads();
  float aq=bq[d], ak=bk[d], av=bv[d];
  const float4* wq4=(const float4*)(Wq + d*D);
  const float4* wk4=(const float4*)(Wk + d*D);
  const float4* wv4=(const float4*)(Wv + d*D);
  #pragma unroll
  for(int e=0;e<16;e++){
    float4 a=wq4[e], b=wk4[e], c=wv4[e];
    aq += lq[4*e]*a.x + lq[4*e+1]*a.y + lq[4*e+2]*a.z + lq[4*e+3]*a.w;
    ak += lk[4*e]*b.x + lk[4*e+1]*b.y + lk[4*e+2]*b.z + lk[4*e+3]*b.w;
    av += lv[4*e]*c.x + lv[4*e+1]*c.y + lv[4*e+2]*c.z + lv[4*e+3]*c.w;
  }
  float nq = sqrtf(waveSum(aq*aq)+1e-15f);
  float qh = tanhf(nq)*aq/nq;
  q_hyp[i*D+d]=qh;
  float q2v = waveSum(qh*qh);
  if(d==0) q2[i]=q2v;
  float nk = sqrtf(waveSum(ak*ak)+1e-15f);
  float kh = tanhf(nk)*ak/nk;
  k_hyp[i*D+d]=kh;
  kT[(size_t)d*S + i]=kh;      // transposed copy (scattered 4B store, ~64 lines/wave)
  float k2v = waveSum(kh*kh);
  if(d==0) k2[i]=k2v;
  vproj[i*D+d]=av;
  kproj[i*D+d]=ak;
  float vr = vrand[i*D+d];
  float nn = sqrtf(waveSum(vr*vr));
  v_r[i*D+d] = vr/fmaxf(nn,1e-12f);
}

// K2 (fused weights+hcent): 2 queries/block, 512 threads.
//  phase 1: coalesced transposed dot sweep -> dist -> min -> w -> wsum -> entropy
//  phase 2: h & centroid in one coalesced float4 sweep, + expmap0(centroid)
__global__ __launch_bounds__(512,4) void k_wc(
  const float* __restrict__ q_hyp, const float* __restrict__ kT,
  const float* __restrict__ q2a, const float* __restrict__ k2a,
  const float* __restrict__ vproj, const float* __restrict__ kproj,
  float* __restrict__ wbuf, float* __restrict__ wsum, float* __restrict__ effm,
  float* __restrict__ h, float* __restrict__ c_hyp, float* __restrict__ c2)
{
  const int i0=blockIdx.x*2, tid=threadIdx.x;
  __shared__ __align__(16) float qv[2][D];
  __shared__ __align__(16) float wl[2][S];
  __shared__ __align__(16) float4 sA[1024];   // phase1 pjoin / phase2 parth
  __shared__ __align__(16) float4 sB[1024];   // phase2 partc
  __shared__ float red[8];
  if(tid<128) qv[tid>>6][tid&63]=q_hyp[i0*D+tid];
  __syncthreads();
  const float x20=q2a[i0], x21=q2a[i0+1];
  const float B0=1.f-x20, B1=1.f-x21;
  const int jf=tid&255, dh=tid>>8;
  const float4* kT4=(const float4*)kT;
  // ---- phase 1a: partial dots (coalesced) ----
  {
    float4 p0={0,0,0,0}, p1={0,0,0,0};
    #pragma unroll 8
    for(int dd=0; dd<32; ++dd){
      const int d=(dh<<5)+dd;
      const float4 y=kT4[d*256+jf];
      const float c0=qv[0][d], c1=qv[1][d];
      p0.x+=c0*y.x; p0.y+=c0*y.y; p0.z+=c0*y.z; p0.w+=c0*y.w;
      p1.x+=c1*y.x; p1.y+=c1*y.y; p1.z+=c1*y.z; p1.w+=c1*y.w;
    }
    sA[(dh*2+0)*256+jf]=p0;
    sA[(dh*2+1)*256+jf]=p1;
  }
  __syncthreads();
  // ---- phase 1b: dist + min (256 combine threads) ----
  float dist[2][4];
  float mn0=FINF, mn1=FINF;
  if(tid<256){
    const float4 qa=sA[jf], qb=sA[512+jf];
    const float4 ra=sA[256+jf], rb=sA[768+jf];
    const float4 y2v=((const float4*)k2a)[jf];
    #pragma unroll
    for(int c=0;c<4;c++){
      const float y2=C4(y2v,c);
      {
        const float dot=C4(qa,c)+C4(qb,c);
        const float A=1.f-2.f*dot+y2;
        const float den=fmaxf(1.f-2.f*dot+x20*y2,1e-15f);
        const float num2=fmaxf(A*A*x20 + B0*B0*y2 - 2.f*A*B0*dot, 0.f);
        const float nn=sqrtf(num2/(den*den)+1e-15f);
        dist[0][c]=2.f*atanhf(fminf(nn,BND));
        mn0=fminf(mn0,dist[0][c]);
      }
      {
        const float dot=C4(ra,c)+C4(rb,c);
        const float A=1.f-2.f*dot+y2;
        const float den=fmaxf(1.f-2.f*dot+x21*y2,1e-15f);
        const float num2=fmaxf(A*A*x21 + B1*B1*y2 - 2.f*A*B1*dot, 0.f);
        const float nn=sqrtf(num2/(den*den)+1e-15f);
        dist[1][c]=2.f*atanhf(fminf(nn,BND));
        mn1=fminf(mn1,dist[1][c]);
      }
    }
  }
  const float m0=blockMin512(mn0,red);
  const float m1=blockMin512(mn1,red);
  float s0=0.f, s1=0.f;
  float w0c[4], w1c[4];
  if(tid<256){
    #pragma unroll
    for(int c=0;c<4;c++){
      w0c[c]=expf(m0-dist[0][c]); s0+=w0c[c];
      w1c[c]=expf(m1-dist[1][c]); s1+=w1c[c];
    }
    ((float4*)&wl[0][0])[jf]=mk4(w0c);
    ((float4*)&wl[1][0])[jf]=mk4(w1c);
    ((float4*)(wbuf+(size_t)i0*S))[jf]=mk4(w0c);
    ((float4*)(wbuf+(size_t)(i0+1)*S))[jf]=mk4(w1c);
  }
  s0=blockSum512(s0,red)+1e-8f;
  s1=blockSum512(s1,red)+1e-8f;
  if(tid==0){ wsum[i0]=s0; wsum[i0+1]=s1; }
  const float inv0=1.f/s0, inv1=1.f/s1;
  float e0=0.f, e1=0.f;
  if(tid<256){
    #pragma unroll
    for(int c=0;c<4;c++){
      const float p0=w0c[c]*inv0; e0 -= p0*logf(p0+1e-8f);
      const float p1=w1c[c]*inv1; e1 -= p1*logf(p1+1e-8f);
    }
  }
  e0=blockSum512(e0,red);
  e1=blockSum512(e1,red);
  if(tid==0){ effm[i0]=expf(e0); effm[i0+1]=expf(e1); }
  // ---- phase 2: h + centroid (coalesced (dq,g) sweep; sA/sB reused as part bufs) ----
  const int dq=tid&15, g=tid>>4;
  float4 ah0={0,0,0,0}, ah1={0,0,0,0}, ac0={0,0,0,0}, ac1={0,0,0,0};
  #pragma unroll 4
  for(int jj=0;jj<32;jj++){
    const int j=jj*32+g;
    const float4 yv=((const float4*)(vproj + j*D))[dq];
    const float4 yk=((const float4*)(kproj + j*D))[dq];
    const float u0=wl[0][j], u1=wl[1][j];
    ah0.x+=u0*yv.x; ah0.y+=u0*yv.y; ah0.z+=u0*yv.z; ah0.w+=u0*yv.w;
    ah1.x+=u1*yv.x; ah1.y+=u1*yv.y; ah1.z+=u1*yv.z; ah1.w+=u1*yv.w;
    ac0.x+=u0*yk.x; ac0.y+=u0*yk.y; ac0.z+=u0*yk.z; ac0.w+=u0*yk.w;
    ac1.x+=u1*yk.x; ac1.y+=u1*yk.y; ac1.z+=u1*yk.z; ac1.w+=u1*yk.w;
  }
  float* pA=(float*)sA;
  float* pB=(float*)sB;
  *(float4*)&pA[(g*2+0)*64+dq*4]=ah0;
  *(float4*)&pA[(g*2+1)*64+dq*4]=ah1;
  *(float4*)&pB[(g*2+0)*64+dq*4]=ac0;
  *(float4*)&pB[(g*2+1)*64+dq*4]=ac1;
  __syncthreads();
  if(tid<128){
    const int q=tid>>6, d=tid&63;
    float hs=0.f, cs=0.f;
    #pragma unroll 8
    for(int gg=0;gg<32;gg++){ hs+=pA[(gg*2+q)*64+d]; cs+=pB[(gg*2+q)*64+d]; }
    const float invq = q ? inv1 : inv0;
    h[(i0+q)*D+d]=hs*invq;
    const float ca=cs*invq;
    const float n=sqrtf(waveSum(ca*ca)+1e-15f);
    const float ch=tanhf(n)*ca/n;
    c_hyp[(i0+q)*D+d]=ch;
    const float c2v=waveSum(ch*ch);
    if(d==0) c2[i0+q]=c2v;
  }
}

// K3 (fused ab+power+final): 2 queries/block, 512 threads.
//  phase A: coalesced transposed dot sweep -> a,b (SoA in LDS), var, tension
//  phase B: 3 power iterations (pass1 transposed-coalesced, pass2 (dq,g)-coalesced)
//  phase C: bifurcation epilogue + output GEMV
__global__ __launch_bounds__(512,4) void k_pmega(
  const float* __restrict__ c_hyp, const float* __restrict__ k_hyp,
  const float* __restrict__ kT,
  const float* __restrict__ c2a, const float* __restrict__ k2a,
  const float* __restrict__ wbuf, const float* __restrict__ wsum,
  const float* __restrict__ effm, const float* __restrict__ tau_p,
  const float* __restrict__ h, const float* __restrict__ q_hyp,
  const float* __restrict__ q2a, const float* __restrict__ v_r,
  const float* __restrict__ gu, const float* __restrict__ gamma_p,
  const float* __restrict__ ts_p, const float* __restrict__ Wo,
  const float* __restrict__ bo, float* __restrict__ out)
{
  const int i0=blockIdx.x*2, tid=threadIdx.x;
  __shared__ __align__(16) float cv[2][D];
  __shared__ __align__(16) float vv[2][D];
  __shared__ __align__(16) float aal[2][S];
  __shared__ __align__(16) float bbl[2][S];
  __shared__ __align__(16) float prow[2][S];
  __shared__ __align__(16) float4 sA[1024];   // pjoin / part alias
  __shared__ __align__(16) float fus[2][D];
  __shared__ float red[8];
  __shared__ float scal[2][4];   // 0:var 1:tension 2:cdot

  if(tid<128){ cv[tid>>6][tid&63]=c_hyp[i0*D+tid]; vv[tid>>6][tid&63]=v_r[i0*D+tid]; }
  __syncthreads();
  const float x20=c2a[i0], x21=c2a[i0+1];
  const float Bc0=1.f-x20, Bc1=1.f-x21;
  const float mB0=fmaxf(Bc0,1e-15f), mB1=fmaxf(Bc1,1e-15f);
  const float inv0=1.f/wsum[i0], inv1=1.f/wsum[i0+1];
  const int jf=tid&255, dh=tid>>8;
  const float4* kT4=(const float4*)kT;

  // ---- phase A ----
  {
    float4 p0={0,0,0,0}, p1={0,0,0,0};
    #pragma unroll 8
    for(int dd=0; dd<32; ++dd){
      const int d=(dh<<5)+dd;
      const float4 y=kT4[d*256+jf];
      const float c0=cv[0][d], c1=cv[1][d];
      p0.x+=c0*y.x; p0.y+=c0*y.y; p0.z+=c0*y.z; p0.w+=c0*y.w;
      p1.x+=c1*y.x; p1.y+=c1*y.y; p1.z+=c1*y.z; p1.w+=c1*y.w;
    }
    sA[(dh*2+0)*256+jf]=p0;
    sA[(dh*2+1)*256+jf]=p1;
  }
  __syncthreads();
  float var0p=0.f, var1p=0.f;
  if(tid<256){
    const float4 qa=sA[jf], qb=sA[512+jf];
    const float4 ra=sA[256+jf], rb=sA[768+jf];
    const float4 y2v=((const float4*)k2a)[jf];
    const float4 w0v=((const float4*)(wbuf+(size_t)i0*S))[jf];
    const float4 w1v=((const float4*)(wbuf+(size_t)(i0+1)*S))[jf];
    float a0c[4],b0c[4],a1c[4],b1c[4];
    #pragma unroll
    for(int c=0;c<4;c++){
      const float y2=C4(y2v,c);
      {
        const float dot=C4(qa,c)+C4(qb,c);
        const float A=1.f-2.f*dot+y2;
        const float den=fmaxf(1.f-2.f*dot+x20*y2,1e-15f);
        const float num2=fmaxf(A*A*x20+Bc0*Bc0*y2-2.f*A*Bc0*dot,0.f);
        const float nn=sqrtf(num2/(den*den)+1e-15f);
        const float art=atanhf(fminf(nn,BND));
        const float w=C4(w0v,c);
        var0p += w*inv0*4.f*art*art;
        const float coef=sqrtf(w+1e-8f)*mB0*art/(nn*den);
        a0c[c]=-coef*A; b0c[c]=coef*Bc0;
      }
      {
        const float dot=C4(ra,c)+C4(rb,c);
        const float A=1.f-2.f*dot+y2;
        const float den=fmaxf(1.f-2.f*dot+x21*y2,1e-15f);
        const float num2=fmaxf(A*A*x21+Bc1*Bc1*y2-2.f*A*Bc1*dot,0.f);
        const float nn=sqrtf(num2/(den*den)+1e-15f);
        const float art=atanhf(fminf(nn,BND));
        const float w=C4(w1v,c);
        var1p += w*inv1*4.f*art*art;
        const float coef=sqrtf(w+1e-8f)*mB1*art/(nn*den);
        a1c[c]=-coef*A; b1c[c]=coef*Bc1;
      }
    }
    ((float4*)&aal[0][0])[jf]=mk4(a0c);
    ((float4*)&aal[1][0])[jf]=mk4(a1c);
    ((float4*)&bbl[0][0])[jf]=mk4(b0c);
    ((float4*)&bbl[1][0])[jf]=mk4(b1c);
  }
  const float var0=blockSum512(var0p,red);
  const float var1=blockSum512(var1p,red);
  if(tid==0){
    scal[0][0]=var0; scal[0][1]=var0 - tau_p[0]*effm[i0];
    scal[1][0]=var1; scal[1][1]=var1 - tau_p[0]*effm[i0+1];
  }

  // ---- phase B: 3 power iterations ----
  const int dq=tid&15, g=tid>>4;
  for(int it=0; it<3; ++it){
    __syncthreads();   // vv ready (and scal/ab on first pass)
    if(tid<128){
      const int q=tid>>6, d=tid&63;
      const float cd=waveSum(cv[q][d]*vv[q][d]);
      if(d==0) scal[q][2]=cd;
    }
    __syncthreads();
    const float cdot0=scal[0][2], cdot1=scal[1][2];
    // pass 1: transposed coalesced dots
    {
      float4 p0={0,0,0,0}, p1={0,0,0,0};
      #pragma unroll 8
      for(int dd=0; dd<32; ++dd){
        const int d=(dh<<5)+dd;
        const float4 y=kT4[d*256+jf];
        const float c0=vv[0][d], c1=vv[1][d];
        p0.x+=c0*y.x; p0.y+=c0*y.y; p0.z+=c0*y.z; p0.w+=c0*y.w;
        p1.x+=c1*y.x; p1.y+=c1*y.y; p1.z+=c1*y.z; p1.w+=c1*y.w;
      }
      sA[(dh*2+0)*256+jf]=p0;
      sA[(dh*2+1)*256+jf]=p1;
    }
    __syncthreads();
    float sal0p=0.f, sal1p=0.f;
    if(tid<256){
      const float4 qa=sA[jf], qb=sA[512+jf];
      const float4 ra=sA[256+jf], rb=sA[768+jf];
      const float4 av0=((float4*)&aal[0][0])[jf];
      const float4 av1=((float4*)&aal[1][0])[jf];
      const float4 bv0=((float4*)&bbl[0][0])[jf];
      const float4 bv1=((float4*)&bbl[1][0])[jf];
      float pr0[4], pr1[4];
      #pragma unroll
      for(int c=0;c<4;c++){
        const float t0=C4(qa,c)+C4(qb,c);
        const float t1=C4(ra,c)+C4(rb,c);
        const float p0=C4(av0,c)*cdot0 + C4(bv0,c)*t0;
        const float p1=C4(av1,c)*cdot1 + C4(bv1,c)*t1;
        pr0[c]=p0*C4(bv0,c); sal0p += p0*C4(av0,c);
        pr1[c]=p1*C4(bv1,c); sal1p += p1*C4(av1,c);
      }
      ((float4*)&prow[0][0])[jf]=mk4(pr0);
      ((float4*)&prow[1][0])[jf]=mk4(pr1);
    }
    const float sal0=blockSum512(sal0p,red);
    const float sal1=blockSum512(sal1p,red);   // syncs also publish prow
    // pass 2: coalesced (dq,g) row-major sweep
    float4 a0={0,0,0,0}, a1={0,0,0,0};
    #pragma unroll 4
    for(int jj=0;jj<32;jj++){
      const int j=jj*32+g;
      const float4 y=((const float4*)(k_hyp + j*D))[dq];
      const float u0=prow[0][j], u1=prow[1][j];
      a0.x+=u0*y.x; a0.y+=u0*y.y; a0.z+=u0*y.z; a0.w+=u0*y.w;
      a1.x+=u1*y.x; a1.y+=u1*y.y; a1.z+=u1*y.z; a1.w+=u1*y.w;
    }
    float* pA=(float*)sA;
    *(float4*)&pA[(g*2+0)*64+dq*4]=a0;
    *(float4*)&pA[(g*2+1)*64+dq*4]=a1;
    __syncthreads();
    if(tid<128){
      const int q=tid>>6, d=tid&63;
      float od=(q?sal1:sal0)*cv[q][d];
      #pragma unroll 8
      for(int gg=0;gg<32;gg++) od += pA[(gg*2+q)*64+d];
      const float nn=sqrtf(waveSum(od*od));
      vv[q][d]=od/fmaxf(nn,1e-12f);
    }
  }
  __syncthreads();

  // ---- phase C: epilogue ----
  if(tid<128){
    const int q=tid>>6, d=tid&63;
    const int i=i0+q;
    const float x2q = q ? x21 : x20;
    const float vd=vv[q][d];
    const float vars=scal[q][0], tns=scal[q][1];
    const float hd=h[i*D+d];
    const float qd=q_hyp[i*D+d];
    const float q2=q2a[i];
    const float wpg=vd/fmaxf(1.f-x2q,1e-15f);
    const float nq=sqrtf(q2+1e-15f);
    const float qt=atanhf(fminf(nq,BND))*qd/nq;
    const float ncn=sqrtf(x2q+1e-15f);
    const float ct=atanhf(fminf(ncn,BND))*cv[q][d]/ncn;
    const float df=qt-ct;
    const float nd=sqrtf(waveSum(df*df));
    const float fb=df/fmaxf(nd,1e-8f);
    const float wp=(vars>1e-5f)?wpg:fb;
    const float hn=sqrtf(waveSum(hd*hd)+1e-15f);
    const float hc=asinhf(hn)*hd/(hn+1e-8f);
    const float x=waveSum(hc*wp);
    const float hmag=sqrtf(waveSum(hc*hc)+1e-15f);
    const float amp=(tns>0.f)? hmag*tanhf(tns) : 0.f;
    const float u0=gu[i*2], u1=gu[i*2+1];
    const float eg=(u0>=u1)?1.f:-1.f;
    const float dc=tanhf(eg*amp - x);
    const float hp=hc+dc*wp;
    const float hpn=sqrtf(waveSum(hp*hp)+1e-15f)+1e-8f;
    const float hpb=hp*(tanhf(hpn*ts_p[0])/hpn);
    const float n2=sqrtf(waveSum(hpb*hpb)+1e-15f);
    const float hyp=tanhf(n2)*hpb/n2;
    const float n3=sqrtf(waveSum(hyp*hyp)+1e-15f);
    const float bif=atanhf(fminf(n3,BND))*hyp/n3;
    const float gate=1.f/(1.f+expf(-gamma_p[0]));
    fus[q][d]=(1.f-gate)*hd + gate*bif;
  }
  __syncthreads();
  if(tid<128){
    const int q=tid>>6, d=tid&63;
    float acc=bo[d];
    const float4* wo4=(const float4*)(Wo + d*D);
    #pragma unroll
    for(int e=0;e<16;e++){
      float4 wv=wo4[e];
      acc += fus[q][4*e]*wv.x + fus[q][4*e+1]*wv.y + fus[q][4*e+2]*wv.z + fus[q][4*e+3]*wv.w;
    }
    out[(i0+q)*D+d]=acc;
  }
}

extern "C" void kernel_launch(void* const* d_in, const int* in_sizes, int n_in,
                              void* d_out, int out_size, void* d_ws, size_t ws_size,
                              hipStream_t stream)
{
  const float* qin=(const float*)d_in[0];
  const float* kin=(const float*)d_in[1];
  const float* vin=(const float*)d_in[2];
  const float* Wq=(const float*)d_in[3];
  const float* bq=(const float*)d_in[4];
  const float* Wk=(const float*)d_in[5];
  const float* bk=(const float*)d_in[6];
  const float* Wv=(const float*)d_in[7];
  const float* bv=(const float*)d_in[8];
  const float* Wo=(const float*)d_in[9];
  const float* bo=(const float*)d_in[10];
  const float* tau=(const float*)d_in[11];
  const float* gamma=(const float*)d_in[12];
  const float* tscale=(const float*)d_in[13];
  const float* gu=(const float*)d_in[14];
  const float* vrand=(const float*)d_in[15];
  float* out=(float*)d_out;

  float* p=(float*)d_ws;
  float* q_hyp=p; p+=S*D;
  float* k_hyp=p; p+=S*D;
  float* kT=p;    p+=S*D;
  float* vproj=p; p+=S*D;
  float* kproj=p; p+=S*D;
  float* v_r=p;   p+=S*D;
  float* h=p;     p+=S*D;
  float* c_hyp=p; p+=S*D;
  float* q2=p;   p+=S;
  float* k2=p;   p+=S;
  float* c2=p;   p+=S;
  float* wsum=p; p+=S;
  float* effm=p; p+=S;
  float* wbuf=p; p+=(size_t)S*S;

  k_proj<<<S,64,0,stream>>>(qin,kin,vin,Wq,bq,Wk,bk,Wv,bv,vrand,
                            q_hyp,k_hyp,kT,vproj,kproj,q2,k2,v_r);
  k_wc<<<S/2,512,0,stream>>>(q_hyp,kT,q2,k2,vproj,kproj,
                             wbuf,wsum,effm,h,c_hyp,c2);
  k_pmega<<<S/2,512,0,stream>>>(c_hyp,k_hyp,kT,c2,k2,wbuf,wsum,effm,tau,
                                h,q_hyp,q2,v_r,gu,gamma,tscale,Wo,bo,out);
}